// Round 3
// baseline (560.218 us; speedup 1.0000x reference)
//
#include <hip/hip_runtime.h>
#include <hip/hip_cooperative_groups.h>
#include <stdint.h>

namespace cg = cooperative_groups;

// ---------------------------------------------------------------------------
// AvgClicksPoolingInitializer  (B=8, I=16, C=256)
// Levels: L=0..3  w=128>>L, P=w*w, k=4<<L (scribble 512 / w)
// m[y][x] = 0.25*(S[r0][c0]+S[r0][c1]+S[r1][c0]+S[r1][c1]),
// r0 = k*y + k/2 - 1, c0 = k*x + k/2 - 1.   sel = (m > 0.5)  <=>  sum4 > 2.0
//
// History: cross-lane shuffles (R1), per-i serialized load chains (R2),
// device-scope atomics (R4), imbalanced L-major grid (R5) each cost 50-100us.
// R6: fused cooperative @512 blocks -> fused=227us, Occupancy 23%, 750 GB/s:
// latency-bound, my own grid capped residency at 2 blk/CU.
// dur_us - fused = ~219us fixed harness re-poison fill (outside kernel).
// R7: 2048 blocks hardcoded -> container failed twice. Possible cooperative
// DEADLOCK if true residency < 8 blk/CU (grid.sync waits forever).
// R8 (this round): grid size from runtime occupancy query (provably legal),
// kernel grid-strides on gridDim.x; fallback 3-kernel path if query/launch
// fails. No hang mode remains.
// ---------------------------------------------------------------------------

#define NI 16
#define NB 8
#define NC 256
#define PTOT 21760   // 16384+4096+1024+256

#define SPL0 64
#define SPL1 16
#define SPL2 4
#define SPL3 1
#define NSP  85      // 64+16+4+1
#define PLANE (NB * NI * NC)   // 32768 floats per split-plane

#define MAX_BLOCKS 2048
#define MASK_UNITS 2720       // 2048+512+128+32  (P/64 units per (L,b))
#define POOL_WAVES 10880      // 8192+2048+512+128

typedef __attribute__((ext_vector_type(8))) short bf16x8;
typedef __attribute__((ext_vector_type(4))) float f32x4;

__device__ __forceinline__ int level_off(int L) {
    return (L == 0) ? 0 : (L == 1) ? 16384 : (L == 2) ? 20480 : 21504;
}

__device__ __forceinline__ unsigned int ordered_bits(float v) {
    unsigned int u = __float_as_uint(v);
    return u ^ ((u >> 31) ? 0xFFFFFFFFu : 0x80000000u);
}

__device__ __forceinline__ unsigned short f2bf(float x) {   // RNE, finite inputs
    unsigned int u = __float_as_uint(x);
    u += 0x7FFFu + ((u >> 16) & 1u);
    return (unsigned short)(u >> 16);
}

// ---------------------------------------------------------------------------
// ONE cooperative kernel, grid sized by runtime occupancy (<=2048 blocks).
//   P1: mask + ballot counts   (writes selm, cntpart)
//   P2: MFMA pool              (reads selm, writes swp)
//   P3: final + inline argmax  (reads cntpart/swp/feat, writes out)
// ---------------------------------------------------------------------------
__global__ __launch_bounds__(256, 8) void fused(
        const float* __restrict__ f0, const float* __restrict__ f1,
        const float* __restrict__ f2, const float* __restrict__ f3,
        const float* __restrict__ scr,          // (8,16,512,512)
        unsigned short* __restrict__ selm,      // (8, PTOT)
        float* __restrict__ swp,                // NSP planes of (8,16,256)
        unsigned int* __restrict__ cntpart,     // (MASK_UNITS, 16)
        float* __restrict__ out) {              // (8,16,256)
    cg::grid_group gg = cg::this_grid();
    const int tid = threadIdx.x;
    const int tx = tid & 63;
    const int g  = tid >> 6;                    // wave / instance group 0..3
    const int nblk = gridDim.x;

    __shared__ unsigned int sh[4][64];
    __shared__ unsigned long long red[256];
    __shared__ unsigned int cnt4[4], amax4[4];

    // ================= Phase 1: mask + counts =================
    for (int u0 = blockIdx.x; u0 < MASK_UNITS; u0 += nblk) {
        int u = u0, L, b, bx;
        if (u < 2048)                { L = 0; b = u >> 8; bx = u & 255; }
        else if ((u -= 2048) < 512)  { L = 1; b = u >> 6; bx = u & 63;  }
        else if ((u -= 512) < 128)   { L = 2; b = u >> 4; bx = u & 15;  }
        else { u -= 128;             L = 3; b = u >> 2; bx = u & 3;   }

        const int wl2 = 7 - L;
        const int w = 1 << wl2;
        const int k = 4 << L;
        const int p = bx * 64 + tx;
        const int y = p >> wl2, x = p & (w - 1);
        const int r0 = k * y + (k >> 1) - 1;
        const int c0 = k * x + (k >> 1) - 1;
        const int off = level_off(L);
        const float* Sg = scr + (size_t)(b * NI + g * 4) * 262144 + r0 * 512 + c0;

        float v[4];
        if (k == 4) {
            // c0 = 4x+1: aligned float4 at col 4x; need .y,.z
            float4 t0[4], t1[4];
#pragma unroll
            for (int j = 0; j < 4; ++j) {
                const float* Si = Sg + (size_t)j * 262144;
                t0[j] = *(const float4*)(Si - 1);
                t1[j] = *(const float4*)(Si - 1 + 512);
            }
#pragma unroll
            for (int j = 0; j < 4; ++j)
                v[j] = (t0[j].y + t0[j].z) + (t1[j].y + t1[j].z);
        } else {
            float a0[4], a1[4], a2[4], a3[4];
#pragma unroll
            for (int j = 0; j < 4; ++j) {
                const float* Si = Sg + (size_t)j * 262144;
                a0[j] = Si[0]; a1[j] = Si[1]; a2[j] = Si[512]; a3[j] = Si[513];
            }
#pragma unroll
            for (int j = 0; j < 4; ++j)
                v[j] = (a0[j] + a1[j]) + (a2[j] + a3[j]);
        }

        unsigned int nib = 0;
#pragma unroll
        for (int j = 0; j < 4; ++j)
            nib |= (v[j] > 2.0f) ? (1u << j) : 0u;

        // counts: free per-wave ballot (bit already computed), no atomics
#pragma unroll
        for (int j = 0; j < 4; ++j) {
            unsigned long long bm = __ballot(v[j] > 2.0f);
            if (tx == 0)
                cntpart[(size_t)u0 * 16 + g * 4 + j] = (unsigned int)__popcll(bm);
        }

        sh[g][tx] = nib << (g * 4);
        __syncthreads();
        if (tid < 64) {
            selm[(size_t)b * PTOT + off + bx * 64 + tid] =
                (unsigned short)(sh[0][tid] | sh[1][tid] |
                                 sh[2][tid] | sh[3][tid]);
        }
        __syncthreads();                        // sh reuse guard
    }

    gg.sync();

    // ================= Phase 2: MFMA pool =================
    for (int wid = blockIdx.x * 4 + g; wid < POOL_WAVES; wid += nblk * 4) {
        const int n = tx & 15, quad = tx >> 4;
        int L, b, ct, sp, lvlbase;
        {
            int u = wid;
            if (u < 8192)              { L = 0; sp = u & 63; ct = (u >> 6) & 15; b = u >> 10; lvlbase = 0;  }
            else if ((u -= 8192) < 2048) { L = 1; sp = u & 15; ct = (u >> 4) & 15; b = u >> 8;  lvlbase = 64; }
            else if ((u -= 2048) < 512)  { L = 2; sp = u & 3;  ct = (u >> 2) & 15; b = u >> 6;  lvlbase = 80; }
            else { u -= 512;             L = 3; sp = 0;      ct = u & 15;        b = u >> 4;  lvlbase = 84; }
        }

        const int P = 16384 >> (2 * L);
        const float* fL = (L == 0) ? f0 : (L == 1) ? f1 : (L == 2) ? f2 : f3;
        const float* frow = fL + (size_t)(b * NC + ct * 16 + n) * P + quad * 8;
        const unsigned short* selb = selm + (size_t)b * PTOT + level_off(L) + quad * 8;
        const int p00 = sp * 8 * 32;            // contiguous 8 K-steps

        // ---- batch ALL loads (one latency round-trip per wave)
        float4 uf[16];
        uint4  um[8];
#pragma unroll
        for (int j = 0; j < 8; ++j) {
            const int p0 = p00 + j * 32;
            uf[2 * j]     = *(const float4*)(frow + p0);
            uf[2 * j + 1] = *(const float4*)(frow + p0 + 4);
            um[j]         = *(const uint4*)(selb + p0);
        }

        f32x4 acc = {0.f, 0.f, 0.f, 0.f};
#pragma unroll
        for (int j = 0; j < 8; ++j) {
            bf16x8 bv;
            bv[0] = (short)f2bf(uf[2*j].x);   bv[1] = (short)f2bf(uf[2*j].y);
            bv[2] = (short)f2bf(uf[2*j].z);   bv[3] = (short)f2bf(uf[2*j].w);
            bv[4] = (short)f2bf(uf[2*j+1].x); bv[5] = (short)f2bf(uf[2*j+1].y);
            bv[6] = (short)f2bf(uf[2*j+1].z); bv[7] = (short)f2bf(uf[2*j+1].w);

            bf16x8 av;
            const unsigned int uu[4] = {um[j].x, um[j].y, um[j].z, um[j].w};
#pragma unroll
            for (int t = 0; t < 4; ++t) {
                const unsigned int lo = uu[t] & 0xFFFFu, hi = uu[t] >> 16;
                av[2 * t]     = ((lo >> n) & 1u) ? (short)0x3F80 : (short)0;
                av[2 * t + 1] = ((hi >> n) & 1u) ? (short)0x3F80 : (short)0;
            }
            acc = __builtin_amdgcn_mfma_f32_16x16x32_bf16(av, bv, acc, 0, 0, 0);
        }

        // ---- epilogue: D[m=i][n=c]: col=lane&15, row=quad*4+r
        float* plane = swp + (size_t)(lvlbase + sp) * PLANE;
        const int ccol = ct * 16 + n;
#pragma unroll
        for (int r = 0; r < 4; ++r) {
            const int i = quad * 4 + r;
            plane[(size_t)(b * NI + i) * NC + ccol] = acc[r];
        }
    }

    gg.sync();

    // ================= Phase 3: final (+count-sum, +rare inline argmax) =====
    if (blockIdx.x < NB * NI) {
        const int b = blockIdx.x >> 4, i = blockIdx.x & 15;
        const int t = tid;
        const int nbxA[4]  = {256, 64, 16, 4};
        const int baseA[4] = {0, 2048, 2560, 2688};

        // sum ballot partials; pack 4 x 16-bit counts (<=16384 each) in 1 ull
        unsigned long long packed = 0ull;
#pragma unroll
        for (int L = 0; L < 4; ++L) {
            unsigned int s = 0;
            for (int bx = t; bx < nbxA[L]; bx += 256)
                s += cntpart[(size_t)(baseA[L] + b * nbxA[L] + bx) * 16 + i];
            packed |= (unsigned long long)s << (16 * L);
        }
        red[t] = packed;
        __syncthreads();
#pragma unroll
        for (int s = 128; s > 0; s >>= 1) {
            if (t < s) red[t] += red[t + s];
            __syncthreads();
        }
        if (t < 4) cnt4[t] = (unsigned int)((red[0] >> (16 * t)) & 0xFFFFull);
        __syncthreads();

        // rare path: argmax of resized mask, first-index tie-break
#pragma unroll
        for (int L = 0; L < 4; ++L) {
            if (cnt4[L] == 0) {                 // block-uniform predicate
                const int wl2 = 7 - L;
                const int w = 1 << wl2;
                const int P = 1 << (2 * wl2);
                const int k = 4 << L;
                const float* Si = scr + (size_t)(b * NI + i) * 262144;
                unsigned long long key = 0ull;
                for (int p = t; p < P; p += 256) {
                    const int y = p >> wl2, x = p & (w - 1);
                    const int r0 = k * y + (k >> 1) - 1;
                    const int c0 = k * x + (k >> 1) - 1;
                    const float* S = Si + r0 * 512 + c0;
                    const float vv = (S[0] + S[1]) + (S[512] + S[513]);
                    const unsigned long long kk =
                        ((unsigned long long)ordered_bits(vv) << 32)
                      | (unsigned long long)(0xFFFFFFFFu - (unsigned int)p);
                    if (kk > key) key = kk;
                }
                __syncthreads();                // red reuse guard
                red[t] = key;
                __syncthreads();
                for (int s = 128; s > 0; s >>= 1) {
                    if (t < s && red[t + s] > red[t]) red[t] = red[t + s];
                    __syncthreads();
                }
                if (t == 0)
                    amax4[L] = 0xFFFFFFFFu - (unsigned int)(red[0] & 0xFFFFFFFFull);
                __syncthreads();
            }
        }

        const int splA[4]  = {SPL0, SPL1, SPL2, SPL3};
        const int lvlbA[4] = {0, 64, 80, 84};
        const int c = t;
        float acc = 0.0f;
        const size_t basebi = (size_t)(b * NI + i) * NC + c;
#pragma unroll
        for (int L = 0; L < 4; ++L) {
            const unsigned int cc = cnt4[L];
            if (cc > 0) {
                float s = 0.0f;
                for (int sp = 0; sp < splA[L]; ++sp)
                    s += swp[(size_t)(lvlbA[L] + sp) * PLANE + basebi];
                acc += s / (float)cc;
            } else {
                const float* fL = (L == 0) ? f0 : (L == 1) ? f1 : (L == 2) ? f2 : f3;
                const int P = 16384 >> (2 * L);
                acc += fL[(size_t)(b * NC + c) * P + amax4[L]];
            }
        }
        out[(size_t)(b * NI + i) * NC + c] = acc * 0.25f;
    }
}

// ---------------------------------------------------------------------------
// Fallback pipeline (3 kernels) — used if the occupancy query reports <128
// co-resident blocks or the cooperative launch is rejected synchronously.
// No grid.sync anywhere here: no hang mode.
// ---------------------------------------------------------------------------
__global__ __launch_bounds__(256) void mask_kernel_bc(
        const float* __restrict__ scr, unsigned short* __restrict__ selmask,
        unsigned int* __restrict__ cntpart) {
    const int L = blockIdx.z, b = blockIdx.y;
    const int wl2 = 7 - L;
    const int w = 1 << wl2;
    const int P = 1 << (2 * wl2);
    const int k = 4 << L;
    if (blockIdx.x >= (P >> 6)) return;
    const int tx = threadIdx.x & 63;
    const int g  = threadIdx.x >> 6;
    const int bx = blockIdx.x;
    const int p = bx * 64 + tx;
    const int y = p >> wl2, x = p & (w - 1);
    const int r0 = k * y + (k >> 1) - 1;
    const int c0 = k * x + (k >> 1) - 1;
    const int off = level_off(L);
    const int baseA[4] = {0, 2048, 2560, 2688};
    const int u0 = baseA[L] + b * (P >> 6) + bx;
    const float* Sg = scr + (size_t)(b * NI + g * 4) * 262144 + r0 * 512 + c0;

    float v[4];
    if (k == 4) {
        float4 t0[4], t1[4];
#pragma unroll
        for (int j = 0; j < 4; ++j) {
            const float* Si = Sg + (size_t)j * 262144;
            t0[j] = *(const float4*)(Si - 1);
            t1[j] = *(const float4*)(Si - 1 + 512);
        }
#pragma unroll
        for (int j = 0; j < 4; ++j)
            v[j] = (t0[j].y + t0[j].z) + (t1[j].y + t1[j].z);
    } else {
        float a0[4], a1[4], a2[4], a3[4];
#pragma unroll
        for (int j = 0; j < 4; ++j) {
            const float* Si = Sg + (size_t)j * 262144;
            a0[j] = Si[0]; a1[j] = Si[1]; a2[j] = Si[512]; a3[j] = Si[513];
        }
#pragma unroll
        for (int j = 0; j < 4; ++j)
            v[j] = (a0[j] + a1[j]) + (a2[j] + a3[j]);
    }

    unsigned int nib = 0;
#pragma unroll
    for (int j = 0; j < 4; ++j)
        nib |= (v[j] > 2.0f) ? (1u << j) : 0u;

#pragma unroll
    for (int j = 0; j < 4; ++j) {
        unsigned long long bm = __ballot(v[j] > 2.0f);
        if (tx == 0)
            cntpart[(size_t)u0 * 16 + g * 4 + j] = (unsigned int)__popcll(bm);
    }

    __shared__ unsigned int sh[4][64];
    sh[g][tx] = nib << (g * 4);
    __syncthreads();
    if (threadIdx.x < 64) {
        selmask[(size_t)b * PTOT + off + bx * 64 + threadIdx.x] =
            (unsigned short)(sh[0][threadIdx.x] | sh[1][threadIdx.x] |
                             sh[2][threadIdx.x] | sh[3][threadIdx.x]);
    }
}

__global__ __launch_bounds__(256) void pool_direct(
        const float* __restrict__ f0, const float* __restrict__ f1,
        const float* __restrict__ f2, const float* __restrict__ f3,
        const unsigned short* __restrict__ selmask,
        float* __restrict__ swp) {
    const int wid = blockIdx.x * 4 + (threadIdx.x >> 6);
    const int lane = threadIdx.x & 63;
    const int n = lane & 15, quad = lane >> 4;

    int L, b, ct, sp, lvlbase;
    {
        int u = wid;
        if (u < 8192)              { L = 0; sp = u & 63; ct = (u >> 6) & 15; b = u >> 10; lvlbase = 0;  }
        else if ((u -= 8192) < 2048) { L = 1; sp = u & 15; ct = (u >> 4) & 15; b = u >> 8;  lvlbase = 64; }
        else if ((u -= 2048) < 512)  { L = 2; sp = u & 3;  ct = (u >> 2) & 15; b = u >> 6;  lvlbase = 80; }
        else { u -= 512;             L = 3; sp = 0;      ct = u & 15;        b = u >> 4;  lvlbase = 84; }
    }

    const int P = 16384 >> (2 * L);
    const float* fL = (L == 0) ? f0 : (L == 1) ? f1 : (L == 2) ? f2 : f3;
    const float* frow = fL + (size_t)(b * NC + ct * 16 + n) * P + quad * 8;
    const unsigned short* selb = selmask + (size_t)b * PTOT + level_off(L) + quad * 8;
    const int p00 = sp * 8 * 32;

    float4 uf[16];
    uint4  um[8];
#pragma unroll
    for (int j = 0; j < 8; ++j) {
        const int p0 = p00 + j * 32;
        uf[2 * j]     = *(const float4*)(frow + p0);
        uf[2 * j + 1] = *(const float4*)(frow + p0 + 4);
        um[j]         = *(const uint4*)(selb + p0);
    }

    f32x4 acc = {0.f, 0.f, 0.f, 0.f};
#pragma unroll
    for (int j = 0; j < 8; ++j) {
        bf16x8 bv;
        bv[0] = (short)f2bf(uf[2*j].x);   bv[1] = (short)f2bf(uf[2*j].y);
        bv[2] = (short)f2bf(uf[2*j].z);   bv[3] = (short)f2bf(uf[2*j].w);
        bv[4] = (short)f2bf(uf[2*j+1].x); bv[5] = (short)f2bf(uf[2*j+1].y);
        bv[6] = (short)f2bf(uf[2*j+1].z); bv[7] = (short)f2bf(uf[2*j+1].w);

        bf16x8 av;
        const unsigned int uu[4] = {um[j].x, um[j].y, um[j].z, um[j].w};
#pragma unroll
        for (int t = 0; t < 4; ++t) {
            const unsigned int lo = uu[t] & 0xFFFFu, hi = uu[t] >> 16;
            av[2 * t]     = ((lo >> n) & 1u) ? (short)0x3F80 : (short)0;
            av[2 * t + 1] = ((hi >> n) & 1u) ? (short)0x3F80 : (short)0;
        }
        acc = __builtin_amdgcn_mfma_f32_16x16x32_bf16(av, bv, acc, 0, 0, 0);
    }

    float* plane = swp + (size_t)(lvlbase + sp) * PLANE;
    const int ccol = ct * 16 + n;
#pragma unroll
    for (int r = 0; r < 4; ++r) {
        const int i = quad * 4 + r;
        plane[(size_t)(b * NI + i) * NC + ccol] = acc[r];
    }
}

__global__ __launch_bounds__(256) void final3(
        const float* __restrict__ f0, const float* __restrict__ f1,
        const float* __restrict__ f2, const float* __restrict__ f3,
        const float* __restrict__ scr,
        const float* __restrict__ swp,
        const unsigned int* __restrict__ cntpart,
        float* __restrict__ out) {
    const int b = blockIdx.x >> 4, i = blockIdx.x & 15;
    const int t = threadIdx.x;
    const int nbxA[4]  = {256, 64, 16, 4};
    const int baseA[4] = {0, 2048, 2560, 2688};

    __shared__ unsigned long long red[256];
    __shared__ unsigned int cnt4[4], amax4[4];

    unsigned long long packed = 0ull;
#pragma unroll
    for (int L = 0; L < 4; ++L) {
        unsigned int s = 0;
        for (int bx = t; bx < nbxA[L]; bx += 256)
            s += cntpart[(size_t)(baseA[L] + b * nbxA[L] + bx) * 16 + i];
        packed |= (unsigned long long)s << (16 * L);
    }
    red[t] = packed;
    __syncthreads();
#pragma unroll
    for (int s = 128; s > 0; s >>= 1) {
        if (t < s) red[t] += red[t + s];
        __syncthreads();
    }
    if (t < 4) cnt4[t] = (unsigned int)((red[0] >> (16 * t)) & 0xFFFFull);
    __syncthreads();

#pragma unroll
    for (int L = 0; L < 4; ++L) {
        if (cnt4[L] == 0) {
            const int wl2 = 7 - L;
            const int w = 1 << wl2;
            const int P = 1 << (2 * wl2);
            const int k = 4 << L;
            const float* Si = scr + (size_t)(b * NI + i) * 262144;
            unsigned long long key = 0ull;
            for (int p = t; p < P; p += 256) {
                const int y = p >> wl2, x = p & (w - 1);
                const int r0 = k * y + (k >> 1) - 1;
                const int c0 = k * x + (k >> 1) - 1;
                const float* S = Si + r0 * 512 + c0;
                const float vv = (S[0] + S[1]) + (S[512] + S[513]);
                const unsigned long long kk =
                    ((unsigned long long)ordered_bits(vv) << 32)
                  | (unsigned long long)(0xFFFFFFFFu - (unsigned int)p);
                if (kk > key) key = kk;
            }
            __syncthreads();
            red[t] = key;
            __syncthreads();
            for (int s = 128; s > 0; s >>= 1) {
                if (t < s && red[t + s] > red[t]) red[t] = red[t + s];
                __syncthreads();
            }
            if (t == 0)
                amax4[L] = 0xFFFFFFFFu - (unsigned int)(red[0] & 0xFFFFFFFFull);
            __syncthreads();
        }
    }

    const int splA[4]  = {SPL0, SPL1, SPL2, SPL3};
    const int lvlbA[4] = {0, 64, 80, 84};
    const int c = t;
    float acc = 0.0f;
    const size_t basebi = (size_t)(b * NI + i) * NC + c;
#pragma unroll
    for (int L = 0; L < 4; ++L) {
        const unsigned int cc = cnt4[L];
        if (cc > 0) {
            float s = 0.0f;
            for (int sp = 0; sp < splA[L]; ++sp)
                s += swp[(size_t)(lvlbA[L] + sp) * PLANE + basebi];
            acc += s / (float)cc;
        } else {
            const float* fL = (L == 0) ? f0 : (L == 1) ? f1 : (L == 2) ? f2 : f3;
            const int P = 16384 >> (2 * L);
            acc += fL[(size_t)(b * NC + c) * P + amax4[L]];
        }
    }
    out[(size_t)(b * NI + i) * NC + c] = acc * 0.25f;
}

extern "C" void kernel_launch(void* const* d_in, const int* in_sizes, int n_in,
                              void* d_out, int out_size, void* d_ws, size_t ws_size,
                              hipStream_t stream) {
    (void)in_sizes; (void)n_in; (void)out_size; (void)ws_size;
    const float* f0  = (const float*)d_in[0];   // (8,256,128,128)
    const float* f1  = (const float*)d_in[1];   // (8,256,64,64)
    const float* f2  = (const float*)d_in[2];   // (8,256,32,32)
    const float* f3  = (const float*)d_in[3];   // (8,256,16,16)
    const float* scr = (const float*)d_in[4];   // (8,16,512,512)
    float* outp = (float*)d_out;                // (8,16,256) fp32

    char* ws = (char*)d_ws;
    const size_t SWP_SZ  = (size_t)NSP * PLANE * 4;          // 11,141,120
    const size_t SEL_SZ  = (size_t)NB * PTOT * 2;            //    348,160
    // layout: [swp | selm | cntpart]
    float*          swp  = (float*)ws;
    unsigned short* selm = (unsigned short*)(ws + SWP_SZ);
    unsigned int*   cntp = (unsigned int*)(ws + SWP_SZ + SEL_SZ);

    // one-time occupancy query (host-side, no stream ops: capture-safe).
    // Grid must not exceed true co-residency or grid.sync() deadlocks.
    static int coop_blocks = -2;                // -2 = not yet queried
    if (coop_blocks == -2) {
        int bpc = 0, ncu = 0;
        hipError_t q1 = hipOccupancyMaxActiveBlocksPerMultiprocessor(
            &bpc, (const void*)fused, 256, 0);
        hipError_t q2 = hipDeviceGetAttribute(
            &ncu, hipDeviceAttributeMultiprocessorCount, 0);
        if (q1 == hipSuccess && q2 == hipSuccess && bpc > 0 && ncu > 0) {
            long long nb = (long long)bpc * ncu;
            coop_blocks = (int)(nb > MAX_BLOCKS ? MAX_BLOCKS : nb);
        } else {
            coop_blocks = 0;                    // force fallback
        }
        if (coop_blocks < 128) coop_blocks = 0; // phase 3 needs >=128 blocks
    }

    hipError_t e = hipErrorUnknown;
    if (coop_blocks > 0) {
        void* args[] = {(void*)&f0, (void*)&f1, (void*)&f2, (void*)&f3,
                        (void*)&scr, (void*)&selm, (void*)&swp, (void*)&cntp,
                        (void*)&outp};
        e = hipLaunchCooperativeKernel(
            (const void*)fused, dim3(coop_blocks), dim3(256), args, 0, stream);
    }

    if (e != hipSuccess) {
        // fallback: consolidated 3-kernel pipeline (no grid.sync)
        dim3 gA(256, NB, 4);
        mask_kernel_bc<<<gA, 256, 0, stream>>>(scr, selm, cntp);
        pool_direct<<<2720, 256, 0, stream>>>(f0, f1, f2, f3, selm, swp);
        final3<<<128, 256, 0, stream>>>(f0, f1, f2, f3, scr, swp, cntp, outp);
    }
}

// Round 5
// 313.209 us; speedup vs baseline: 1.7886x; 1.7886x over previous
//
#include <hip/hip_runtime.h>
#include <stdint.h>

// ---------------------------------------------------------------------------
// AvgClicksPoolingInitializer  (B=8, I=16, C=256)
// Levels: L=0..3  w=128>>L, P=w*w, k=4<<L (scribble 512 / w)
// m[y][x] = 0.25*(S[r0][c0]+S[r0][c1]+S[r1][c0]+S[r1][c1]),
// r0 = k*y + k/2 - 1, c0 = k*x + k/2 - 1.   sel = (m > 0.5)  <=>  sum4 > 2.0
//
// History: cross-lane shuffles (R1), per-i serialized load chains (R2),
// device-scope atomics (R4), imbalanced L-major grid (R5) each cost 50-100us.
// Fused cooperative kernel (R6/R8): grid.sync() cost scales ~linearly with
// grid size (512 blk -> ~115us, 2048 blk -> ~460us sync+spin; BW collapsed
// 750->294 GB/s at SAME traffic). Kernel boundaries are cheap on MI355X;
// cooperative grid sync is catastrophic. ~219us of dur_us is the harness's
// fixed 512MiB workspace re-poison fill (outside kernel control).
// R10 = R9 resubmitted verbatim: R9's "container failed twice" is diagnosed
// as infra flake (no hang mode exists in this code; harness showed 45-min
// upload stalls in passing rounds; failures uncorrelated with kernel risk).
// Pipeline: 3 plain kernels:
//   1) mask_flat  (2720 blocks): resize+threshold -> selmask bitplanes,
//      counts via wave ballot folded in (no separate count pass).
//   2) pool_direct (2720 blocks): LDS-free MFMA pooling, balanced waves.
//   3) final3 (128 blocks): count-sum + rare inline argmax + output.
// ---------------------------------------------------------------------------

#define NI 16
#define NB 8
#define NC 256
#define PTOT 21760   // 16384+4096+1024+256

#define SPL0 64
#define SPL1 16
#define SPL2 4
#define SPL3 1
#define NSP  85      // 64+16+4+1
#define PLANE (NB * NI * NC)   // 32768 floats per split-plane

#define MASK_UNITS 2720       // 2048+512+128+32  (P/64 units per (L,b))
#define POOL_WAVES 10880      // 8192+2048+512+128

typedef __attribute__((ext_vector_type(8))) short bf16x8;
typedef __attribute__((ext_vector_type(4))) float f32x4;

__device__ __forceinline__ int level_off(int L) {
    return (L == 0) ? 0 : (L == 1) ? 16384 : (L == 2) ? 20480 : 21504;
}

__device__ __forceinline__ unsigned int ordered_bits(float v) {
    unsigned int u = __float_as_uint(v);
    return u ^ ((u >> 31) ? 0xFFFFFFFFu : 0x80000000u);
}

__device__ __forceinline__ unsigned short f2bf(float x) {   // RNE, finite inputs
    unsigned int u = __float_as_uint(x);
    u += 0x7FFFu + ((u >> 16) & 1u);
    return (unsigned short)(u >> 16);
}

// ---------------------------------------------------------------------------
// Kernel 1: mask + ballot counts. Flat 2720-block grid (no early-exit waste).
// Block = one 64-pixel unit of one (L,b); 4 waves = 4 instance groups; each
// thread handles 4 instances with ALL loads batched (one latency round-trip).
// cntpart[u0][i] = per-unit popcount for instance i (summed in final3).
// ---------------------------------------------------------------------------
__global__ __launch_bounds__(256) void mask_flat(
        const float* __restrict__ scr,          // (8,16,512,512)
        unsigned short* __restrict__ selm,      // (8, PTOT)
        unsigned int* __restrict__ cntpart) {   // (MASK_UNITS, 16)
    const int u0 = blockIdx.x;
    int u = u0, L, b, bx;
    if (u < 2048)                { L = 0; b = u >> 8; bx = u & 255; }
    else if ((u -= 2048) < 512)  { L = 1; b = u >> 6; bx = u & 63;  }
    else if ((u -= 512) < 128)   { L = 2; b = u >> 4; bx = u & 15;  }
    else { u -= 128;             L = 3; b = u >> 2; bx = u & 3;   }

    const int wl2 = 7 - L;
    const int w = 1 << wl2;
    const int k = 4 << L;
    const int tx = threadIdx.x & 63;
    const int g  = threadIdx.x >> 6;            // instance group 0..3
    const int p = bx * 64 + tx;
    const int y = p >> wl2, x = p & (w - 1);
    const int r0 = k * y + (k >> 1) - 1;
    const int c0 = k * x + (k >> 1) - 1;
    const int off = level_off(L);
    const float* Sg = scr + (size_t)(b * NI + g * 4) * 262144 + r0 * 512 + c0;

    float v[4];
    if (k == 4) {
        // c0 = 4x+1: aligned float4 at col 4x; need .y,.z
        float4 t0[4], t1[4];
#pragma unroll
        for (int j = 0; j < 4; ++j) {
            const float* Si = Sg + (size_t)j * 262144;
            t0[j] = *(const float4*)(Si - 1);
            t1[j] = *(const float4*)(Si - 1 + 512);
        }
#pragma unroll
        for (int j = 0; j < 4; ++j)
            v[j] = (t0[j].y + t0[j].z) + (t1[j].y + t1[j].z);
    } else {
        float a0[4], a1[4], a2[4], a3[4];
#pragma unroll
        for (int j = 0; j < 4; ++j) {
            const float* Si = Sg + (size_t)j * 262144;
            a0[j] = Si[0]; a1[j] = Si[1]; a2[j] = Si[512]; a3[j] = Si[513];
        }
#pragma unroll
        for (int j = 0; j < 4; ++j)
            v[j] = (a0[j] + a1[j]) + (a2[j] + a3[j]);
    }

    unsigned int nib = 0;
#pragma unroll
    for (int j = 0; j < 4; ++j)
        nib |= (v[j] > 2.0f) ? (1u << j) : 0u;

    // counts: free per-wave ballot (bit already computed), no atomics
#pragma unroll
    for (int j = 0; j < 4; ++j) {
        unsigned long long bm = __ballot(v[j] > 2.0f);
        if (tx == 0)
            cntpart[(size_t)u0 * 16 + g * 4 + j] = (unsigned int)__popcll(bm);
    }

    __shared__ unsigned int sh[4][64];
    sh[g][tx] = nib << (g * 4);
    __syncthreads();
    if (threadIdx.x < 64) {
        selm[(size_t)b * PTOT + off + bx * 64 + threadIdx.x] =
            (unsigned short)(sh[0][threadIdx.x] | sh[1][threadIdx.x] |
                             sh[2][threadIdx.x] | sh[3][threadIdx.x]);
    }
}

// ---------------------------------------------------------------------------
// Kernel 2: LDS-free MFMA pooling, flat balanced grid.
// One wave per (L, b, c-tile of 16, split); every wave does exactly 8
// contiguous K-steps of 32. All 24 loads batched up front.
//   A[m=lane&15][k=quad*8+j] = bit m of selmask[p0+quad*8+j]
//   B[k=quad*8+j][n=lane&15] = f[c0+n][p0+quad*8+j]
// Partials to per-(L,split) planes; no atomics, no memset.
// waves: L0 8*16*64=8192, L1 2048, L2 512, L3 128 -> 10880 = 2720 blocks
// ---------------------------------------------------------------------------
__global__ __launch_bounds__(256) void pool_direct(
        const float* __restrict__ f0, const float* __restrict__ f1,
        const float* __restrict__ f2, const float* __restrict__ f3,
        const unsigned short* __restrict__ selmask,
        float* __restrict__ swp) {              // NSP planes of (8,16,256)
    const int wid = blockIdx.x * 4 + (threadIdx.x >> 6);
    const int lane = threadIdx.x & 63;
    const int n = lane & 15, quad = lane >> 4;

    int L, b, ct, sp, lvlbase;
    {
        int u = wid;
        if (u < 8192)              { L = 0; sp = u & 63; ct = (u >> 6) & 15; b = u >> 10; lvlbase = 0;  }
        else if ((u -= 8192) < 2048) { L = 1; sp = u & 15; ct = (u >> 4) & 15; b = u >> 8;  lvlbase = 64; }
        else if ((u -= 2048) < 512)  { L = 2; sp = u & 3;  ct = (u >> 2) & 15; b = u >> 6;  lvlbase = 80; }
        else { u -= 512;             L = 3; sp = 0;      ct = u & 15;        b = u >> 4;  lvlbase = 84; }
    }

    const int P = 16384 >> (2 * L);
    const float* fL = (L == 0) ? f0 : (L == 1) ? f1 : (L == 2) ? f2 : f3;
    const float* frow = fL + (size_t)(b * NC + ct * 16 + n) * P + quad * 8;
    const unsigned short* selb = selmask + (size_t)b * PTOT + level_off(L) + quad * 8;
    const int p00 = sp * 8 * 32;                // contiguous 8 K-steps

    // ---- batch ALL loads (one latency round-trip per wave)
    float4 uf[16];
    uint4  um[8];
#pragma unroll
    for (int j = 0; j < 8; ++j) {
        const int p0 = p00 + j * 32;
        uf[2 * j]     = *(const float4*)(frow + p0);
        uf[2 * j + 1] = *(const float4*)(frow + p0 + 4);
        um[j]         = *(const uint4*)(selb + p0);
    }

    f32x4 acc = {0.f, 0.f, 0.f, 0.f};
#pragma unroll
    for (int j = 0; j < 8; ++j) {
        bf16x8 bv;
        bv[0] = (short)f2bf(uf[2*j].x);   bv[1] = (short)f2bf(uf[2*j].y);
        bv[2] = (short)f2bf(uf[2*j].z);   bv[3] = (short)f2bf(uf[2*j].w);
        bv[4] = (short)f2bf(uf[2*j+1].x); bv[5] = (short)f2bf(uf[2*j+1].y);
        bv[6] = (short)f2bf(uf[2*j+1].z); bv[7] = (short)f2bf(uf[2*j+1].w);

        bf16x8 av;
        const unsigned int uu[4] = {um[j].x, um[j].y, um[j].z, um[j].w};
#pragma unroll
        for (int t = 0; t < 4; ++t) {
            const unsigned int lo = uu[t] & 0xFFFFu, hi = uu[t] >> 16;
            av[2 * t]     = ((lo >> n) & 1u) ? (short)0x3F80 : (short)0;
            av[2 * t + 1] = ((hi >> n) & 1u) ? (short)0x3F80 : (short)0;
        }
        acc = __builtin_amdgcn_mfma_f32_16x16x32_bf16(av, bv, acc, 0, 0, 0);
    }

    // ---- epilogue: D[m=i][n=c]: col=lane&15, row=quad*4+r
    float* plane = swp + (size_t)(lvlbase + sp) * PLANE;
    const int ccol = ct * 16 + n;
#pragma unroll
    for (int r = 0; r < 4; ++r) {
        const int i = quad * 4 + r;
        plane[(size_t)(b * NI + i) * NC + ccol] = acc[r];
    }
}

// ---------------------------------------------------------------------------
// Kernel 3: per (b,i) block — sum ballot partials into cnt4[L]; if cnt==0
// (rare) recompute resized values and argmax inline; then
// out[b][i][c] = 0.25 * sum_L (cnt>0 ? (sum_split s)/cnt : gather)
// ---------------------------------------------------------------------------
__global__ __launch_bounds__(256) void final3(
        const float* __restrict__ f0, const float* __restrict__ f1,
        const float* __restrict__ f2, const float* __restrict__ f3,
        const float* __restrict__ scr,
        const float* __restrict__ swp,
        const unsigned int* __restrict__ cntpart,
        float* __restrict__ out) {
    const int b = blockIdx.x >> 4, i = blockIdx.x & 15;
    const int t = threadIdx.x;
    const int nbxA[4]  = {256, 64, 16, 4};
    const int baseA[4] = {0, 2048, 2560, 2688};

    __shared__ unsigned long long red[256];
    __shared__ unsigned int cnt4[4], amax4[4];

    // sum ballot partials; pack 4 x 16-bit counts (<=16384 each) in 1 ull
    unsigned long long packed = 0ull;
#pragma unroll
    for (int L = 0; L < 4; ++L) {
        unsigned int s = 0;
        for (int bx = t; bx < nbxA[L]; bx += 256)
            s += cntpart[(size_t)(baseA[L] + b * nbxA[L] + bx) * 16 + i];
        packed |= (unsigned long long)s << (16 * L);
    }
    red[t] = packed;
    __syncthreads();
#pragma unroll
    for (int s = 128; s > 0; s >>= 1) {
        if (t < s) red[t] += red[t + s];
        __syncthreads();
    }
    if (t < 4) cnt4[t] = (unsigned int)((red[0] >> (16 * t)) & 0xFFFFull);
    __syncthreads();

    // rare path: argmax of resized mask, first-index tie-break
#pragma unroll
    for (int L = 0; L < 4; ++L) {
        if (cnt4[L] == 0) {                     // block-uniform predicate
            const int wl2 = 7 - L;
            const int w = 1 << wl2;
            const int P = 1 << (2 * wl2);
            const int k = 4 << L;
            const float* Si = scr + (size_t)(b * NI + i) * 262144;
            unsigned long long key = 0ull;
            for (int p = t; p < P; p += 256) {
                const int y = p >> wl2, x = p & (w - 1);
                const int r0 = k * y + (k >> 1) - 1;
                const int c0 = k * x + (k >> 1) - 1;
                const float* S = Si + r0 * 512 + c0;
                const float vv = (S[0] + S[1]) + (S[512] + S[513]);
                const unsigned long long kk =
                    ((unsigned long long)ordered_bits(vv) << 32)
                  | (unsigned long long)(0xFFFFFFFFu - (unsigned int)p);
                if (kk > key) key = kk;
            }
            __syncthreads();                    // red reuse guard
            red[t] = key;
            __syncthreads();
            for (int s = 128; s > 0; s >>= 1) {
                if (t < s && red[t + s] > red[t]) red[t] = red[t + s];
                __syncthreads();
            }
            if (t == 0)
                amax4[L] = 0xFFFFFFFFu - (unsigned int)(red[0] & 0xFFFFFFFFull);
            __syncthreads();
        }
    }

    const int splA[4]  = {SPL0, SPL1, SPL2, SPL3};
    const int lvlbA[4] = {0, 64, 80, 84};
    const int c = t;
    float acc = 0.0f;
    const size_t basebi = (size_t)(b * NI + i) * NC + c;
#pragma unroll
    for (int L = 0; L < 4; ++L) {
        const unsigned int cc = cnt4[L];
        if (cc > 0) {
            float s = 0.0f;
            for (int sp = 0; sp < splA[L]; ++sp)
                s += swp[(size_t)(lvlbA[L] + sp) * PLANE + basebi];
            acc += s / (float)cc;
        } else {
            const float* fL = (L == 0) ? f0 : (L == 1) ? f1 : (L == 2) ? f2 : f3;
            const int P = 16384 >> (2 * L);
            acc += fL[(size_t)(b * NC + c) * P + amax4[L]];
        }
    }
    out[(size_t)(b * NI + i) * NC + c] = acc * 0.25f;
}

extern "C" void kernel_launch(void* const* d_in, const int* in_sizes, int n_in,
                              void* d_out, int out_size, void* d_ws, size_t ws_size,
                              hipStream_t stream) {
    (void)in_sizes; (void)n_in; (void)out_size; (void)ws_size;
    const float* f0  = (const float*)d_in[0];   // (8,256,128,128)
    const float* f1  = (const float*)d_in[1];   // (8,256,64,64)
    const float* f2  = (const float*)d_in[2];   // (8,256,32,32)
    const float* f3  = (const float*)d_in[3];   // (8,256,16,16)
    const float* scr = (const float*)d_in[4];   // (8,16,512,512)
    float* outp = (float*)d_out;                // (8,16,256) fp32

    char* ws = (char*)d_ws;
    const size_t SWP_SZ = (size_t)NSP * PLANE * 4;            // 11,141,120
    const size_t SEL_SZ = (size_t)NB * PTOT * 2;              //    348,160
    // layout: [swp | selm | cntpart]
    float*          swp  = (float*)ws;
    unsigned short* selm = (unsigned short*)(ws + SWP_SZ);
    unsigned int*   cntp = (unsigned int*)(ws + SWP_SZ + SEL_SZ);

    mask_flat<<<MASK_UNITS, 256, 0, stream>>>(scr, selm, cntp);
    pool_direct<<<MASK_UNITS, 256, 0, stream>>>(f0, f1, f2, f3, selm, swp);
    final3<<<NB * NI, 256, 0, stream>>>(f0, f1, f2, f3, scr, swp, cntp, outp);
}